// Round 1
// baseline (119.775 us; speedup 1.0000x reference)
//
#include <hip/hip_runtime.h>

typedef __bf16 bf16x8 __attribute__((ext_vector_type(8)));
typedef float f32x4 __attribute__((ext_vector_type(4)));

#define TB 256
#define PTS_PER_BLOCK 1024   // 4 waves * 16 groups * 16 pts
#define GROUPS 16

// round-to-nearest-even float -> bf16 bits (low 16)
__device__ __forceinline__ unsigned int bf16rn(float f) {
  unsigned int u = __float_as_uint(f);
  return (u + 0x7fffu + ((u >> 16) & 1u)) >> 16;
}

__device__ __forceinline__ float2 unpk(unsigned int u) {
  return make_float2(__uint_as_float(u << 16), __uint_as_float(u & 0xffff0000u));
}
__device__ __forceinline__ float2 f2max0(float2 a) {
  return make_float2(fmaxf(a.x, 0.f), fmaxf(a.y, 0.f));
}

// Pre-kernel: convert lines (3,128,32) fp32 -> bf16 into ws with row stride 40
// (80 B, keeps every row-chunk 16B-aligned and spreads rows over 8 bank groups)
__global__ void cvt_tables(const float* __restrict__ lines, unsigned short* __restrict__ ws) {
  int i = blockIdx.x * TB + threadIdx.x;
  if (i >= 3 * 128 * 32) return;
  int d = i >> 12;          // / 4096
  int rem = i & 4095;
  int r = rem >> 5;         // / 32
  int c = rem & 31;
  ws[d * 5120 + r * 40 + c] = (unsigned short)bf16rn(lines[i]);
}

__global__ __launch_bounds__(TB) void fused_kernel(
    const float* __restrict__ coords, const unsigned short* __restrict__ tabws,
    const float* __restrict__ W1, const float* __restrict__ b1,
    const float* __restrict__ W2, const float* __restrict__ b2,
    float* __restrict__ out, int M)
{
  __shared__ alignas(16) unsigned short tab[3 * 128 * 40]; // 30720 B
  {
    const uint4* src = (const uint4*)tabws;
    uint4* dst = (uint4*)tab;
    #pragma unroll 2
    for (int i = threadIdx.x; i < 1920; i += TB) dst[i] = src[i];
  }

  const int lane = threadIdx.x & 63;
  const int wv   = threadIdx.x >> 6;
  const int col  = lane & 15;   // A-row / C-col index
  const int q    = lane >> 4;   // quad: A k-octet / C row-group

  // One-time register-resident W1 B-fragments: B[k][n] = W1[n][k]
  // lane holds W1[col+16t][q*8 .. q*8+7] as bf16x8
  bf16x8 bfrag[8];
  #pragma unroll
  for (int t = 0; t < 8; ++t) {
    const float* wr = W1 + (col + 16 * t) * 32 + q * 8;
    uint4 pu;
    pu.x = bf16rn(wr[0]) | (bf16rn(wr[1]) << 16);
    pu.y = bf16rn(wr[2]) | (bf16rn(wr[3]) << 16);
    pu.z = bf16rn(wr[4]) | (bf16rn(wr[5]) << 16);
    pu.w = bf16rn(wr[6]) | (bf16rn(wr[7]) << 16);
    union { uint4 u; bf16x8 v; } cvt; cvt.u = pu; bfrag[t] = cvt.v;
  }
  float2 b1v[4], w2v[4];
  #pragma unroll
  for (int u = 0; u < 4; ++u) {
    b1v[u] = make_float2(b1[col + 32 * u], b1[col + 32 * u + 16]);
    w2v[u] = make_float2(W2[col + 32 * u], W2[col + 32 * u + 16]);
  }
  const float vb2 = b2[0];
  __syncthreads();

  const char* tb = (const char*)tab + q * 16; // this lane's 16B chunk within a row
  const int wave_base = blockIdx.x * PTS_PER_BLOCK + wv * (GROUPS * 16);

  #pragma unroll 2
  for (int g = 0; g < GROUPS; ++g) {
    const int p0 = wave_base + g * 16;
    const int p  = p0 + col;            // this lane's point (A-row m = col)
    const float* cp = coords + p * 3;
    const float cx = cp[0], cy = cp[1], cz = cp[2];

    // align_corners bilinear setup; coords in [-1,1) so taps always in range
    const float posx = (cx + 1.0f) * 63.5f;
    const float posy = (cy + 1.0f) * 63.5f;
    const float posz = (cz + 1.0f) * 63.5f;
    const int ix = min((int)posx, 126);
    const int iy = min((int)posy, 126);
    const int iz = min((int)posz, 126);
    const float frx = posx - (float)ix;
    const float fry = posy - (float)iy;
    const float frz = posz - (float)iz;

    const uint4* gx = (const uint4*)(tb + ix * 80);
    const uint4* gy = (const uint4*)(tb + 10240 + iy * 80);
    const uint4* gz = (const uint4*)(tb + 20480 + iz * 80);
    const uint4 x0 = gx[0], x1 = gx[5];   // +5 uint4 = +80 B = next row
    const uint4 y0 = gy[0], y1 = gy[5];
    const uint4 z0 = gz[0], z1 = gz[5];

    const float2 w0x = make_float2(1.f - frx, 1.f - frx), w1x = make_float2(frx, frx);
    const float2 w0y = make_float2(1.f - fry, 1.f - fry), w1y = make_float2(fry, fry);
    const float2 w0z = make_float2(1.f - frz, 1.f - frz), w1z = make_float2(frz, frz);

    const unsigned int X0[4] = {x0.x, x0.y, x0.z, x0.w};
    const unsigned int X1[4] = {x1.x, x1.y, x1.z, x1.w};
    const unsigned int Y0[4] = {y0.x, y0.y, y0.z, y0.w};
    const unsigned int Y1[4] = {y1.x, y1.y, y1.z, y1.w};
    const unsigned int Z0[4] = {z0.x, z0.y, z0.z, z0.w};
    const unsigned int Z1[4] = {z1.x, z1.y, z1.z, z1.w};

    unsigned int au[4];
    const float2 C1 = make_float2(2.5f, 2.5f);    // 1/RANGE
    const float2 C2 = make_float2(6.25f, 6.25f);  // 1/RANGE^2
    #pragma unroll
    for (int k = 0; k < 4; ++k) {
      float2 xe = unpk(X0[k]) * w0x + unpk(X1[k]) * w1x;
      float2 ye = unpk(Y0[k]) * w0y + unpk(Y1[k]) * w1y;
      float2 ze = unpk(Z0[k]) * w0z + unpk(Z1[k]) * w1z;
      float2 t  = xe + ye;
      float2 s1 = t + ze;
      float2 xy = xe * ye;
      float2 pr = ze * t + xy;     // xy + xz + yz
      float2 xyz = xy * ze;
      float2 f  = s1 + pr * C1 + xyz * C2;
      // pack 2 channels: truncate both floats to bf16 in one v_perm
      au[k] = __builtin_amdgcn_perm(__float_as_uint(f.y), __float_as_uint(f.x), 0x07060302u);
    }
    union { uint4 u; bf16x8 v; } av;
    av.u = make_uint4(au[0], au[1], au[2], au[3]);

    const f32x4 zacc = {0.f, 0.f, 0.f, 0.f};
    f32x4 c[8];
    #pragma unroll
    for (int t = 0; t < 8; ++t)
      c[t] = __builtin_amdgcn_mfma_f32_16x16x32_bf16(av.v, bfrag[t], zacc, 0, 0, 0);

    // epilogue: relu(h + b1) . W2, lane holds h-col = col+16t for points q*4+r
    float sr[4];
    #pragma unroll
    for (int r = 0; r < 4; ++r) {
      float2 a2 = make_float2(0.f, 0.f);
      #pragma unroll
      for (int u = 0; u < 4; ++u) {
        float2 hv = make_float2(c[2 * u][r], c[2 * u + 1][r]) + b1v[u];
        hv = f2max0(hv);
        a2 = a2 + hv * w2v[u];
      }
      sr[r] = a2.x + a2.y;
    }
    // reduce across the 16 col-lanes (xor bits 0..3 stay within the q-group)
    #pragma unroll
    for (int d = 1; d < 16; d <<= 1) {
      #pragma unroll
      for (int r = 0; r < 4; ++r) sr[r] += __shfl_xor(sr[r], d, 64);
    }
    // lanes col=0..3 of each quad store points p0 + q*4 + col (coalesced 64B)
    const int j = lane & 3;
    float v01 = (j & 1) ? sr[1] : sr[0];
    float v23 = (j & 1) ? sr[3] : sr[2];
    float v   = (j & 2) ? v23 : v01;
    if (col < 4) out[p0 + q * 4 + j] = v + vb2;
  }
}

extern "C" void kernel_launch(void* const* d_in, const int* in_sizes, int n_in,
                              void* d_out, int out_size, void* d_ws, size_t ws_size,
                              hipStream_t stream) {
  const float* coords = (const float*)d_in[0];
  const float* lines  = (const float*)d_in[1];
  const float* W1     = (const float*)d_in[2];
  const float* b1     = (const float*)d_in[3];
  const float* W2     = (const float*)d_in[4];
  const float* b2     = (const float*)d_in[5];
  float* out = (float*)d_out;
  const int M = in_sizes[0] / 3;

  unsigned short* tabws = (unsigned short*)d_ws;
  cvt_tables<<<48, TB, 0, stream>>>(lines, tabws);
  const int blocks = (M + PTS_PER_BLOCK - 1) / PTS_PER_BLOCK;
  fused_kernel<<<blocks, TB, 0, stream>>>(coords, tabws, W1, b1, W2, b2, out, M);
}